// Round 4
// baseline (156.293 us; speedup 1.0000x reference)
//
#include <hip/hip_runtime.h>
#include <cstdint>
#include <cstddef>

// Problem constants
#define NCLUS 64
#define DIM   128
#define BATCH 512              // K of the Gram reduction (bytes per fp8 row)
#define QCOLS 8192             // NCLUS*DIM
#define NSUPER 528             // 32*33/2 supergroup pairs (gj<=gi)
#define TSTRB (QCOLS * BATCH)  // BYTES per tensor in fp8 (4,194,304)
#define FP8SCALE 256.0f        // q^2 * 256 -> e4m3 (max 256 < 448, no clip)

typedef float f32x16 __attribute__((ext_vector_type(16)));
typedef int   i32x4  __attribute__((ext_vector_type(4)));
typedef int   i32x8  __attribute__((ext_vector_type(8)));

// q2t layout: row (t, c*128+d) of 512 bytes over b, PLAIN byte order.
// LDS rows store the 4 16-B chunks of each 64-B k-slice rotated by
// rot(r)=(r+(r>>2))&3 (bank-checked in the 127us baseline: 2-way = free);
// achieved by pre-swizzling the GLOBAL source address (LDS dest linear).

__device__ __forceinline__ void ld_lds16(const void* g, void* l) {
  __builtin_amdgcn_global_load_lds(
      (__attribute__((address_space(1))) void*)g,
      (__attribute__((address_space(3))) void*)l, 16, 0, 0);
}

#define VM4_BAR() asm volatile("s_waitcnt vmcnt(4)\n\ts_barrier" ::: "memory")
#define VM0_BAR() asm volatile("s_waitcnt vmcnt(0)\n\ts_barrier" ::: "memory")

// ---------------------------------------------------------------------------
// Kernel 1: softmax over D=128 -> q^2*256 -> fp8 e4m3 -> transposed q2t
// (plain byte order). EXACT round-0 structure (256 threads, 64-batch tile,
// 64B-coalesced transposed writes) — the 512-thread variant regressed.
// ---------------------------------------------------------------------------
__global__ __launch_bounds__(256) void softmax_q2_kernel(
    const float* __restrict__ emb, uint8_t* __restrict__ q2t,
    float* __restrict__ dotPart) {
  __shared__ uint32_t T32[2 * 64 * 33];      // 16.5 KB; [t*64+b][col] stride 33
  __shared__ float red[4];
  const int c  = blockIdx.y;
  const int bq = blockIdx.x;
  const int tid = threadIdx.x;
  const int w = tid >> 6, lane = tid & 63;
  const int sub = lane >> 5;                 // which of the 2 rows this iter
  const int col = lane & 31;                 // float4 index within the row

  float4 qa = {0.f, 0.f, 0.f, 0.f};
  float dot = 0.f;

#pragma unroll
  for (int k = 0; k < 16; ++k) {
    const int t  = k & 1;
    const int bl = w * 16 + (k >> 1) * 2 + sub;   // 0..63
    const int b  = bq * 64 + bl;
    const float4 v = *(const float4*)(emb +
        ((size_t)(t * BATCH + b) * QCOLS + (size_t)c * DIM + col * 4));

    float mx = fmaxf(fmaxf(v.x, v.y), fmaxf(v.z, v.w));
#pragma unroll
    for (int off = 1; off < 32; off <<= 1) mx = fmaxf(mx, __shfl_xor(mx, off));
    float e0 = __expf(v.x - mx), e1 = __expf(v.y - mx);
    float e2 = __expf(v.z - mx), e3 = __expf(v.w - mx);
    float s = (e0 + e1) + (e2 + e3);
#pragma unroll
    for (int off = 1; off < 32; off <<= 1) s += __shfl_xor(s, off);
    const float inv = 1.0f / s;
    const float q0 = e0 * inv, q1 = e1 * inv, q2 = e2 * inv, q3 = e3 * inv;

    if (t == 0) { qa.x = q0; qa.y = q1; qa.z = q2; qa.w = q3; }
    else        { dot += qa.x * q0 + qa.y * q1 + qa.z * q2 + qa.w * q3; }

    int pk = __builtin_amdgcn_cvt_pk_fp8_f32(q0 * q0 * FP8SCALE,
                                             q1 * q1 * FP8SCALE, 0, false);
    pk = __builtin_amdgcn_cvt_pk_fp8_f32(q2 * q2 * FP8SCALE,
                                         q3 * q3 * FP8SCALE, pk, true);
    T32[(t * 64 + bl) * 33 + col] = (uint32_t)pk;
  }
  __syncthreads();

  // write-out: 1024 chunks of 16 B, PLAIN order: chunk b16 = b [b16*16,+16)
#pragma unroll
  for (int it = 0; it < 4; ++it) {
    int ch = it * 256 + tid;               // 0..1023
    int t = ch >> 9, d = (ch >> 2) & 127, b16 = ch & 3;
    const int dq = d >> 2, sh = (d & 3) * 8;
    uint32_t w0 = 0, w1 = 0, w2 = 0, w3 = 0;
#pragma unroll
    for (int r = 0; r < 4; ++r) {
      w0 |= ((T32[(t * 64 + b16 * 16 +  0 + r) * 33 + dq] >> sh) & 0xFFu) << (8 * r);
      w1 |= ((T32[(t * 64 + b16 * 16 +  4 + r) * 33 + dq] >> sh) & 0xFFu) << (8 * r);
      w2 |= ((T32[(t * 64 + b16 * 16 +  8 + r) * 33 + dq] >> sh) & 0xFFu) << (8 * r);
      w3 |= ((T32[(t * 64 + b16 * 16 + 12 + r) * 33 + dq] >> sh) & 0xFFu) << (8 * r);
    }
    size_t off = (size_t)t * TSTRB + (size_t)(c * DIM + d) * BATCH +
                 (size_t)bq * 64 + b16 * 16;
    uint4 o; o.x = w0; o.y = w1; o.z = w2; o.w = w3;
    *(uint4*)(q2t + off) = o;
  }

#pragma unroll
  for (int off = 1; off < 64; off <<= 1) dot += __shfl_xor(dot, off);
  if (lane == 0) red[w] = dot;
  __syncthreads();
  if (tid == 0) dotPart[blockIdx.y * 8 + blockIdx.x] = red[0] + red[1] + red[2] + red[3];
}

// ---------------------------------------------------------------------------
// Kernel 2: 2x2 cluster SUPERTILE Gram. Block = supergroup pair (gj<=gi):
// A = clusters {2gj,2gj+1} (256 contiguous rows), B = {2gi,2gi+1}.
// Off-diag (gj<gi): full 256x256 = 4 valid pair-tiles. Diag (gj==gi): only
// quadrant (2g, 2g+1) is harvested (waves wm==0,wn>=2); other waves skip
// compute (wave-uniform branch) but still stage + barrier.
// 8 waves (2x4): wave owns 128x64 -> acc[4][2] f32x16, 8 MFMA per 64-B
// k-chunk between barriers (2x the old ratio); staged bytes per MFMA halved.
// Triple-buffered LDS (3x32 KB), ONE s_barrier/step, vmcnt(4) counted,
// stage issued 2 steps ahead (race-free: reads of buf[(m-1)%3] drained
// before barrier(m); stage(m+2) targets that buffer after barrier(m)).
// ---------------------------------------------------------------------------
__global__ __launch_bounds__(512, 2) void gram_super_kernel(
    const uint8_t* __restrict__ q2t, float* __restrict__ Spart) {
  __shared__ uint8_t L[3 * 32768 + 32];  // buf k at k*32768: A@+0, B@+16384

  // ---- decode: XCD partition (528 = 66*8 exact) + triangular (gi,gj) ----
  int sidx = ((int)blockIdx.x & 7) * 66 + ((int)blockIdx.x >> 3);
  int gi = 0;
  while ((gi + 1) * (gi + 2) / 2 <= sidx) ++gi;
  int gj = sidx - gi * (gi + 1) / 2;          // gj <= gi
  const bool diag = (gi == gj);

  const uint8_t* baseA = q2t + (size_t)gj * (256 * BATCH);  // 128 KB panel
  const uint8_t* baseB = q2t + (size_t)gi * (256 * BATCH);

  const int tid  = threadIdx.x;
  const int lane = tid & 63, w = tid >> 6;
  const int wm = w & 1, wn = w >> 1;          // 2x4 wave grid

  // staging: slot tid covers (row rs in 0..127, phys p=tid&3); row rs+128
  // has the SAME rot (128+x + (128+x)>>2 == x + x>>2 mod 4).
  const int rs = tid >> 2;
  const int rot_s = (rs + (rs >> 2)) & 3;
  const int cs = ((tid & 3) - rot_s) & 3;
  const size_t gsrc = (size_t)rs * BATCH + cs * 16;
  uint8_t* Lb = L;
  const int ldsw = w * 1024;   // wave-uniform dest base within an 8 KB region

  // reader: lane h=lane>>5 needs global chunks {2h,2h+1} of each 64-B row;
  // rot depends only on r31 (row bases are multiples of 32).
  const int h = lane >> 5, r31 = lane & 31;
  const int rot = (r31 + (r31 >> 2)) & 3;
  const int ro1 = ((2 * h + rot) & 3) * 16;
  const int ro2 = ((2 * h + 1 + rot) & 3) * 16;
  const int ArO = (wm * 128 + r31) * 64;           // + mi*2048
  const int BrO = 16384 + (wn * 64 + r31) * 64;    // + nj*2048

  // diag blocks: only waves with wm==0 && wn>=2 own the (2g,2g+1) quadrant
  const bool take = !diag || (wm == 0 && wn >= 2);

  f32x16 acc[4][2];
#pragma unroll
  for (int i = 0; i < 4; ++i)
#pragma unroll
    for (int j = 0; j < 2; ++j) acc[i][j] = (f32x16)(0.f);

  float S0 = 0.f, S1 = 0.f;

#define CHOFF64(i) ((size_t)((i) >> 3) * TSTRB + (size_t)((i) & 7) * 64)
#define STAGE(bufb, ck) do {                                           \
    ld_lds16(baseA + (ck) + gsrc,         Lb + (bufb) + ldsw);         \
    ld_lds16(baseA + (ck) + gsrc + 65536, Lb + (bufb) + 8192 + ldsw);  \
    ld_lds16(baseB + (ck) + gsrc,         Lb + (bufb) + 16384 + ldsw); \
    ld_lds16(baseB + (ck) + gsrc + 65536, Lb + (bufb) + 24576 + ldsw); \
  } while (0)
#define MFMA(a, b, c) __builtin_amdgcn_mfma_scale_f32_32x32x64_f8f6f4(        \
    (a), (b), (c), 0, 0, 0, 0x7F7F7F7F, 0, 0x7F7F7F7F)
#define CAT8(lo, hi) __builtin_shufflevector((lo), (hi), 0, 1, 2, 3, 4, 5, 6, 7)

  // prologue: chunks 0,1 into buf0,buf1 (8 loads/thread in flight)
  STAGE(0, CHOFF64(0));
  STAGE(32768, CHOFF64(1));

#pragma unroll
  for (int m = 0; m < 16; ++m) {
    if (m < 15) VM4_BAR(); else VM0_BAR();     // stage(m) landed

    if (m < 14) STAGE(((m + 2) % 3) * 32768, CHOFF64(m + 2));

    if (take) {
      const int be = (m % 3) * 32768;
      i32x8 af[4], bf[2];
#pragma unroll
      for (int mi = 0; mi < 4; ++mi) {
        i32x4 lo = *(const i32x4*)(Lb + be + ArO + mi * 2048 + ro1);
        i32x4 hi = *(const i32x4*)(Lb + be + ArO + mi * 2048 + ro2);
        af[mi] = CAT8(lo, hi);
      }
#pragma unroll
      for (int nj = 0; nj < 2; ++nj) {
        i32x4 lo = *(const i32x4*)(Lb + be + BrO + nj * 2048 + ro1);
        i32x4 hi = *(const i32x4*)(Lb + be + BrO + nj * 2048 + ro2);
        bf[nj] = CAT8(lo, hi);
      }
      __builtin_amdgcn_s_setprio(1);
#pragma unroll
      for (int mi = 0; mi < 4; ++mi)
#pragma unroll
        for (int nj = 0; nj < 2; ++nj)
          acc[mi][nj] = MFMA(af[mi], bf[nj], acc[mi][nj]);
      __builtin_amdgcn_s_setprio(0);
    }

    if (m == 7) {                              // tensor 0 done
      if (take) {
#pragma unroll
        for (int i = 0; i < 4; ++i)
#pragma unroll
          for (int j = 0; j < 2; ++j)
#pragma unroll
            for (int e = 0; e < 16; ++e) S0 += sqrtf(acc[i][j][e]);
      }
#pragma unroll
      for (int i = 0; i < 4; ++i)
#pragma unroll
        for (int j = 0; j < 2; ++j) acc[i][j] = (f32x16)(0.f);
    }
  }

  if (take) {
#pragma unroll
    for (int i = 0; i < 4; ++i)
#pragma unroll
      for (int j = 0; j < 2; ++j)
#pragma unroll
        for (int e = 0; e < 16; ++e) S1 += sqrtf(acc[i][j][e]);
  }

  // G was scaled by 256*256 -> sqrt scaled by 256
  float local = (S0 + S1) * (1.0f / 256.0f);
#pragma unroll
  for (int off = 1; off < 64; off <<= 1) local += __shfl_xor(local, off);
  float* fred = (float*)(L + 3 * 32768);
  if (lane == 0) fred[w] = local;
  __syncthreads();
  if (tid == 0) {
    float t = 0.f;
#pragma unroll
    for (int i = 0; i < 8; ++i) t += fred[i];
    Spart[blockIdx.x] = t;
  }
}

// ---------------------------------------------------------------------------
// Kernel 3: reduce partials and combine.
// P[0..511] = dot partials, P[512..512+527] = S partials (one per super).
// loss = -dot/(B*N_C) - S/((N_C^2-N_C)*sqrt(B))
// ---------------------------------------------------------------------------
__global__ __launch_bounds__(256) void finalize_kernel(
    const float* __restrict__ P, float* __restrict__ out) {
  __shared__ float rd[8];
  const int tid = threadIdx.x;
  float d = 0.f, s = 0.f;
  for (int i = tid; i < 512; i += 256) d += P[i];
  for (int i = tid; i < NSUPER; i += 256) s += P[512 + i];
#pragma unroll
  for (int off = 1; off < 64; off <<= 1) { d += __shfl_xor(d, off); s += __shfl_xor(s, off); }
  const int w = tid >> 6;
  if ((tid & 63) == 0) { rd[w] = d; rd[4 + w] = s; }
  __syncthreads();
  if (tid == 0) {
    float dt = rd[0] + rd[1] + rd[2] + rd[3];
    float st = rd[4] + rd[5] + rd[6] + rd[7];
    out[0] = -dt / 32768.0f - st / (4032.0f * 22.62741699796952f);
  }
}

extern "C" void kernel_launch(void* const* d_in, const int* in_sizes, int n_in,
                              void* d_out, int out_size, void* d_ws, size_t ws_size,
                              hipStream_t stream) {
  const float* emb = (const float*)d_in[0];
  float* out = (float*)d_out;
  float* P = (float*)d_ws;                                 // 512 + 528 partials
  uint8_t* q2t = (uint8_t*)d_ws + 16384;                   // 2 x 8192 x 512 fp8

  softmax_q2_kernel<<<dim3(8, 64), 256, 0, stream>>>(emb, q2t, P);
  gram_super_kernel<<<dim3(NSUPER), 512, 0, stream>>>(q2t, P + 512);
  finalize_kernel<<<1, 256, 0, stream>>>(P, out);
}

// Round 5
// 113.699 us; speedup vs baseline: 1.3746x; 1.3746x over previous
//
#include <hip/hip_runtime.h>
#include <cstdint>
#include <cstddef>

// Problem constants
#define NCLUS 64
#define DIM   128
#define BATCH 512              // K of the Gram reduction (bytes per fp8 row)
#define QCOLS 8192             // NCLUS*DIM
#define NPAIR 2016             // 64*63/2
#define TSTRB (QCOLS * BATCH)  // BYTES per tensor in fp8 (4,194,304)
#define FP8SCALE 256.0f        // q^2 * 256 -> e4m3 (max 256 < 448, no clip)

typedef float f32x16 __attribute__((ext_vector_type(16)));
typedef int   i32x4  __attribute__((ext_vector_type(4)));
typedef int   i32x8  __attribute__((ext_vector_type(8)));

// q2t layout: row (t, c*128+d) of 512 bytes over b, PLAIN byte order.
// LDS rows store the 4 16-B chunks of each 64-B k-slice rotated by
// rot(r)=(r+(r>>2))&3 (bank-checked: 2-way = free); achieved by
// pre-swizzling the GLOBAL source address (LDS dest linear).

__device__ __forceinline__ void ld_lds16(const void* g, void* l) {
  __builtin_amdgcn_global_load_lds(
      (__attribute__((address_space(1))) void*)g,
      (__attribute__((address_space(3))) void*)l, 16, 0, 0);
}

// raw v_sqrt_f32 (1-2 ULP) — sqrtf's IEEE fixup (~6 insts) was ~17us of
// VALU issue across the 66M-element harvest (R2: VALUBusy 62%).
#define FSQRT(x) __builtin_amdgcn_sqrtf(x)

#define VM4_BAR() asm volatile("s_waitcnt vmcnt(4)\n\ts_barrier" ::: "memory")
#define VM0_BAR() asm volatile("s_waitcnt vmcnt(0)\n\ts_barrier" ::: "memory")

// ---------------------------------------------------------------------------
// Kernel 1: softmax over D=128 -> q^2*256 -> fp8 e4m3 -> transposed q2t
// (plain byte order). EXACT round-0 structure (256 threads, 64-batch tile,
// 64B-coalesced transposed writes).
// ---------------------------------------------------------------------------
__global__ __launch_bounds__(256) void softmax_q2_kernel(
    const float* __restrict__ emb, uint8_t* __restrict__ q2t,
    float* __restrict__ dotPart) {
  __shared__ uint32_t T32[2 * 64 * 33];      // 16.5 KB; [t*64+b][col] stride 33
  __shared__ float red[4];
  const int c  = blockIdx.y;
  const int bq = blockIdx.x;
  const int tid = threadIdx.x;
  const int w = tid >> 6, lane = tid & 63;
  const int sub = lane >> 5;                 // which of the 2 rows this iter
  const int col = lane & 31;                 // float4 index within the row

  float4 qa = {0.f, 0.f, 0.f, 0.f};
  float dot = 0.f;

#pragma unroll
  for (int k = 0; k < 16; ++k) {
    const int t  = k & 1;
    const int bl = w * 16 + (k >> 1) * 2 + sub;   // 0..63
    const int b  = bq * 64 + bl;
    const float4 v = *(const float4*)(emb +
        ((size_t)(t * BATCH + b) * QCOLS + (size_t)c * DIM + col * 4));

    float mx = fmaxf(fmaxf(v.x, v.y), fmaxf(v.z, v.w));
#pragma unroll
    for (int off = 1; off < 32; off <<= 1) mx = fmaxf(mx, __shfl_xor(mx, off));
    float e0 = __expf(v.x - mx), e1 = __expf(v.y - mx);
    float e2 = __expf(v.z - mx), e3 = __expf(v.w - mx);
    float s = (e0 + e1) + (e2 + e3);
#pragma unroll
    for (int off = 1; off < 32; off <<= 1) s += __shfl_xor(s, off);
    const float inv = 1.0f / s;
    const float q0 = e0 * inv, q1 = e1 * inv, q2 = e2 * inv, q3 = e3 * inv;

    if (t == 0) { qa.x = q0; qa.y = q1; qa.z = q2; qa.w = q3; }
    else        { dot += qa.x * q0 + qa.y * q1 + qa.z * q2 + qa.w * q3; }

    int pk = __builtin_amdgcn_cvt_pk_fp8_f32(q0 * q0 * FP8SCALE,
                                             q1 * q1 * FP8SCALE, 0, false);
    pk = __builtin_amdgcn_cvt_pk_fp8_f32(q2 * q2 * FP8SCALE,
                                         q3 * q3 * FP8SCALE, pk, true);
    T32[(t * 64 + bl) * 33 + col] = (uint32_t)pk;
  }
  __syncthreads();

  // write-out: 1024 chunks of 16 B, PLAIN order: chunk b16 = b [b16*16,+16)
#pragma unroll
  for (int it = 0; it < 4; ++it) {
    int ch = it * 256 + tid;               // 0..1023
    int t = ch >> 9, d = (ch >> 2) & 127, b16 = ch & 3;
    const int dq = d >> 2, sh = (d & 3) * 8;
    uint32_t w0 = 0, w1 = 0, w2 = 0, w3 = 0;
#pragma unroll
    for (int r = 0; r < 4; ++r) {
      w0 |= ((T32[(t * 64 + b16 * 16 +  0 + r) * 33 + dq] >> sh) & 0xFFu) << (8 * r);
      w1 |= ((T32[(t * 64 + b16 * 16 +  4 + r) * 33 + dq] >> sh) & 0xFFu) << (8 * r);
      w2 |= ((T32[(t * 64 + b16 * 16 +  8 + r) * 33 + dq] >> sh) & 0xFFu) << (8 * r);
      w3 |= ((T32[(t * 64 + b16 * 16 + 12 + r) * 33 + dq] >> sh) & 0xFFu) << (8 * r);
    }
    size_t off = (size_t)t * TSTRB + (size_t)(c * DIM + d) * BATCH +
                 (size_t)bq * 64 + b16 * 16;
    uint4 o; o.x = w0; o.y = w1; o.z = w2; o.w = w3;
    *(uint4*)(q2t + off) = o;
  }

#pragma unroll
  for (int off = 1; off < 64; off <<= 1) dot += __shfl_xor(dot, off);
  if (lane == 0) red[w] = dot;
  __syncthreads();
  if (tid == 0) dotPart[blockIdx.y * 8 + blockIdx.x] = red[0] + red[1] + red[2] + red[3];
}

// ---------------------------------------------------------------------------
// Kernel 2: MX-scaled fp8 Gram tile (J,I), J<I — the VALIDATED round-2
// structure (55.3 us): 128x128 tile, 4 waves (2x2), triple-buffered LDS
// (3x16 KB -> 3 blocks/CU), ONE s_barrier per K-step, vmcnt(4) counted,
// stage issued 2 steps ahead, setprio around the MFMA quad.
// This round's surgical change: harvest uses raw v_sqrt_f32 (FSQRT) with
// 4 independent partial accumulators — the sqrtf fixup expansion was the
// dominant VALU-issue consumer (62% VALUBusy).
// ---------------------------------------------------------------------------
__global__ __launch_bounds__(256) void gram_sqrt_kernel(
    const uint8_t* __restrict__ q2t, float* __restrict__ Spart) {
  __shared__ uint8_t L[3 * 16384 + 16];  // buf k at k*16384: A@+0, B@+8192

  // ---- pair decode: XCD partition + 8x8 supertile order ----
  int sidx = ((int)blockIdx.x & 7) * 252 + ((int)blockIdx.x >> 3);
  int q = sidx, gi = 0;
  while (q >= 64 * gi + 28) { q -= 64 * gi + 28; ++gi; }
  int I, J;
  if (q < 64 * gi) {
    int gj = q >> 6, r = q & 63;
    I = gi * 8 + (r >> 3);
    J = gj * 8 + (r & 7);
  } else {
    int dq = q - 64 * gi;
    int il = 1;
    while (il * (il + 1) / 2 <= dq) ++il;
    I = gi * 8 + il;
    J = gi * 8 + (dq - il * (il - 1) / 2);
  }

  const uint8_t* baseA = q2t + (size_t)J * (DIM * BATCH);  // 64 KB panels
  const uint8_t* baseB = q2t + (size_t)I * (DIM * BATCH);

  const int tid  = threadIdx.x;
  const int lane = tid & 63, w = tid >> 6;
  const int wm = w & 1, wn = w >> 1;

  // staging: slot tid covers (row r, phys p) <- global chunk c=(p-rot(r))&3
  const int t0 = tid, t1 = 256 + tid;
  const int r0s = t0 >> 2, r1s = t1 >> 2;
  const int rot0 = (r0s + (r0s >> 2)) & 3;
  const int rot1 = (r1s + (r1s >> 2)) & 3;
  const int c0s = ((t0 & 3) - rot0) & 3;
  const int c1s = ((t1 & 3) - rot1) & 3;
  const size_t g0 = (size_t)r0s * BATCH + c0s * 16;
  const size_t g1 = (size_t)r1s * BATCH + c1s * 16;
  uint8_t* Lb = L;
  const int ldsw = w * 1024;   // wave-uniform dest base within a 4 KB round

  // reader: row R = wm*64 + g*32 + r31; rot(R) == (r31+(r31>>2))&3.
  // lane h needs global chunks {2h, 2h+1} at phys ((q+rot)&3)*16.
  const int h = lane >> 5, r31 = lane & 31;
  const int rot = (r31 + (r31 >> 2)) & 3;
  const int ro1 = ((2 * h + rot) & 3) * 16;       // chunk 2h   (k h*32..+16)
  const int ro2 = ((2 * h + 1 + rot) & 3) * 16;   // chunk 2h+1 (k h*32+16..+16)
  const int ArowO = (wm * 64 + r31) * 64;         // + g*2048
  const int BrowO = 8192 + (wn * 64 + r31) * 64;  // + g*2048

  f32x16 acc[2][2];
#pragma unroll
  for (int i = 0; i < 2; ++i)
#pragma unroll
    for (int j = 0; j < 2; ++j) acc[i][j] = (f32x16)(0.f);

  float S0 = 0.f, S1 = 0.f;

#define CHOFF64(i) ((size_t)((i) >> 3) * TSTRB + (size_t)((i) & 7) * 64)
#define STAGE(bufb, ck) do {                                       \
    ld_lds16(baseA + (ck) + g0, Lb + (bufb) + ldsw);               \
    ld_lds16(baseA + (ck) + g1, Lb + (bufb) + 4096 + ldsw);        \
    ld_lds16(baseB + (ck) + g0, Lb + (bufb) + 8192 + ldsw);        \
    ld_lds16(baseB + (ck) + g1, Lb + (bufb) + 12288 + ldsw);       \
  } while (0)
#define MFMA(a, b, c) __builtin_amdgcn_mfma_scale_f32_32x32x64_f8f6f4(        \
    (a), (b), (c), 0, 0, 0, 0x7F7F7F7F, 0, 0x7F7F7F7F)

  // prologue: chunks 0,1 into buf0,buf1  (8 loads in flight)
  STAGE(0, CHOFF64(0));
  STAGE(16384, CHOFF64(1));

#pragma unroll
  for (int m = 0; m < 16; ++m) {
    // stage(m) landed (only stage(m+1)'s 4 loads may remain outstanding)
    if (m < 15) VM4_BAR(); else VM0_BAR();

    // prefetch chunk m+2 into buf (m+2)%3 == buf (m-1)%3 (reads drained)
    if (m < 14) STAGE(((m + 2) % 3) * 16384, CHOFF64(m + 2));

    const int be = (m % 3) * 16384;
    i32x4 alo[2], ahi[2], blo[2], bhi[2];
#pragma unroll
    for (int g = 0; g < 2; ++g) {
      alo[g] = *(const i32x4*)(Lb + be + ArowO + g * 2048 + ro1);
      ahi[g] = *(const i32x4*)(Lb + be + ArowO + g * 2048 + ro2);
      blo[g] = *(const i32x4*)(Lb + be + BrowO + g * 2048 + ro1);
      bhi[g] = *(const i32x4*)(Lb + be + BrowO + g * 2048 + ro2);
    }
    i32x8 af[2], bf[2];
#pragma unroll
    for (int g = 0; g < 2; ++g) {
      af[g] = (i32x8){alo[g].x, alo[g].y, alo[g].z, alo[g].w,
                      ahi[g].x, ahi[g].y, ahi[g].z, ahi[g].w};
      bf[g] = (i32x8){blo[g].x, blo[g].y, blo[g].z, blo[g].w,
                      bhi[g].x, bhi[g].y, bhi[g].z, bhi[g].w};
    }
    // ONE scaled MFMA per acc per 64-B chunk; fmt 0 = fp8 e4m3, scale 2^0
    __builtin_amdgcn_s_setprio(1);
#pragma unroll
    for (int i = 0; i < 2; ++i)
#pragma unroll
      for (int j = 0; j < 2; ++j)
        acc[i][j] = MFMA(af[i], bf[j], acc[i][j]);
    __builtin_amdgcn_s_setprio(0);

    if (m == 7) {                       // harvest tensor 0, reset acc
      float p0 = 0.f, p1 = 0.f, p2 = 0.f, p3 = 0.f;
#pragma unroll
      for (int i = 0; i < 2; ++i)
#pragma unroll
        for (int j = 0; j < 2; ++j) {
#pragma unroll
          for (int e = 0; e < 16; e += 4) {
            p0 += FSQRT(acc[i][j][e    ]);
            p1 += FSQRT(acc[i][j][e + 1]);
            p2 += FSQRT(acc[i][j][e + 2]);
            p3 += FSQRT(acc[i][j][e + 3]);
          }
          acc[i][j] = (f32x16)(0.f);
        }
      S0 = (p0 + p1) + (p2 + p3);
    }
  }

  // harvest tensor 1
  {
    float p0 = 0.f, p1 = 0.f, p2 = 0.f, p3 = 0.f;
#pragma unroll
    for (int i = 0; i < 2; ++i)
#pragma unroll
      for (int j = 0; j < 2; ++j)
#pragma unroll
        for (int e = 0; e < 16; e += 4) {
          p0 += FSQRT(acc[i][j][e    ]);
          p1 += FSQRT(acc[i][j][e + 1]);
          p2 += FSQRT(acc[i][j][e + 2]);
          p3 += FSQRT(acc[i][j][e + 3]);
        }
    S1 = (p0 + p1) + (p2 + p3);
  }

  // G was scaled by 256*256 -> sqrt scaled by 256
  float local = (S0 + S1) * (1.0f / 256.0f);
#pragma unroll
  for (int off = 1; off < 64; off <<= 1) local += __shfl_xor(local, off);
  float* fred = (float*)(L + 3 * 16384);
  if (lane == 0) fred[w] = local;
  __syncthreads();
  if (tid == 0) Spart[blockIdx.x] = fred[0] + fred[1] + fred[2] + fred[3];
}

// ---------------------------------------------------------------------------
// Kernel 3: reduce partials and combine.
// P[0..511] = dot partials, P[512..2527] = S partials.
// loss = -dot/(B*N_C) - S/((N_C^2-N_C)*sqrt(B))
// ---------------------------------------------------------------------------
__global__ __launch_bounds__(256) void finalize_kernel(
    const float* __restrict__ P, float* __restrict__ out) {
  __shared__ float rd[8];
  const int tid = threadIdx.x;
  float d = 0.f, s = 0.f;
  for (int i = tid; i < 512; i += 256) d += P[i];
  for (int i = tid; i < NPAIR; i += 256) s += P[512 + i];
#pragma unroll
  for (int off = 1; off < 64; off <<= 1) { d += __shfl_xor(d, off); s += __shfl_xor(s, off); }
  const int w = tid >> 6;
  if ((tid & 63) == 0) { rd[w] = d; rd[4 + w] = s; }
  __syncthreads();
  if (tid == 0) {
    float dt = rd[0] + rd[1] + rd[2] + rd[3];
    float st = rd[4] + rd[5] + rd[6] + rd[7];
    out[0] = -dt / 32768.0f - st / (4032.0f * 22.62741699796952f);
  }
}

extern "C" void kernel_launch(void* const* d_in, const int* in_sizes, int n_in,
                              void* d_out, int out_size, void* d_ws, size_t ws_size,
                              hipStream_t stream) {
  const float* emb = (const float*)d_in[0];
  float* out = (float*)d_out;
  float* P = (float*)d_ws;                                 // 2528 partials
  uint8_t* q2t = (uint8_t*)d_ws + 16384;                   // 2 x 8192 x 512 fp8

  softmax_q2_kernel<<<dim3(8, 64), 256, 0, stream>>>(emb, q2t, P);
  gram_sqrt_kernel<<<dim3(NPAIR), 256, 0, stream>>>(q2t, P + 512);
  finalize_kernel<<<1, 256, 0, stream>>>(P, out);
}